// Round 3
// baseline (263.516 us; speedup 1.0000x reference)
//
#include <hip/hip_runtime.h>

// QuantumRegressionModel: 16-qubit statevector, 3 layers x (16 rotations + CNOT chain),
// PauliZ features + linear head. Batch 64, DIM 65536, fp32.
//
// Reductions (carried from round 2, all verified absmax=0):
//  * Rotations in a layer commute -> split wires {6..15} (kP, wave-local bits 9..0) and
//    wires {0..5} (kQ, regs = bits 15..12 + shuffles for bits 11,10).
//  * CNOT chain == Gray gather psi_new[j] = psi_old[j ^ (j>>1)] -> folded into the NEXT
//    kP's load addressing (float4-window permutation + component swizzle).
//  * Features on pre-perm state: sign_q(m) = (-1)^{parity(m >> (15-q))} -> fused into final kQ.
//  * Final state never materialized.
//
// Round-3 change: 16 amps/thread (was 32) -> 4096 waves = 16 waves/CU (was 8).
// Latency-bound fix: double TLP/MLP; all loads/stores >= 64B-line coalesced.
//
// Wire q <-> global index bit (15-q).
// kP layout: block = m{15..12} (tile) x batch; waves = m{11,10}; lanes = m{7..2};
//            regs: k = m{9,8}, e = m{1,0} (float4 I/O). Gates: w6,w7 (k bits),
//            w8..13 (lane shuffles), w14,w15 (e bits).
// kQ layout: block = m{7,6,1,0} x batch; waves = m{9,8}; lanes = m{11,10,5..2};
//            regs r = m{15..12}. Gates: w0..3 (reg bits), w4,w5 (lane shuffles).

struct G8 { float r00,i00,r01,i01,r10,i10,r11,i11; };

__device__ __forceinline__ G8 loadG(const float* __restrict__ p) {
  G8 g;
  g.r00=p[0]; g.i00=p[1]; g.r01=p[2]; g.i01=p[3];
  g.r10=p[4]; g.i10=p[5]; g.r11=p[6]; g.i11=p[7];
  return g;
}

__device__ __forceinline__ void cmul2(const G8& g, float& r0, float& i0, float& r1, float& i1) {
  const float nr0 = g.r00*r0 - g.i00*i0 + g.r01*r1 - g.i01*i1;
  const float ni0 = g.r00*i0 + g.i00*r0 + g.r01*i1 + g.i01*r1;
  const float nr1 = g.r10*r0 - g.i10*i0 + g.r11*r1 - g.i11*i1;
  const float ni1 = g.r10*i0 + g.i10*r0 + g.r11*i1 + g.i11*r1;
  r0=nr0; i0=ni0; r1=nr1; i1=ni1;
}

// Build 48 fused unitaries U = Rz(tz)Ry(ty)Rx(tx); zero feats accumulator.
__global__ void kPrep(const float* __restrict__ vp, float* __restrict__ U,
                      float* __restrict__ feats) {
  const int i = threadIdx.x;
  if (i < 48) {
    const float tx = vp[i*6+0], ty = vp[i*6+1], tz = vp[i*6+2];
    float sx, cx, sy, cy, sz, cz;
    sincosf(0.5f*tx, &sx, &cx);
    sincosf(0.5f*ty, &sy, &cy);
    sincosf(0.5f*tz, &sz, &cz);
    const float m00r = cy*cx,  m00i = sy*sx;
    const float m01r = -sy*cx, m01i = -cy*sx;
    const float m10r = sy*cx,  m10i = -cy*sx;
    const float m11r = cy*cx,  m11i = -sy*sx;
    float* o = U + i*8;
    o[0] = cz*m00r + sz*m00i;  o[1] = cz*m00i - sz*m00r;
    o[2] = cz*m01r + sz*m01i;  o[3] = cz*m01i - sz*m01r;
    o[4] = cz*m10r - sz*m10i;  o[5] = cz*m10i + sz*m10r;
    o[6] = cz*m11r - sz*m11i;  o[7] = cz*m11i + sz*m11r;
  }
  for (int j = i; j < 1024; j += 64) feats[j] = 0.f;
}

// kP: wires 6..15 (bits 9..0), 16 amps/thread. GATHER folds prev layer's perm into loads.
template<int GATHER>
__global__ void __launch_bounds__(256) kP(const float* __restrict__ sr, const float* __restrict__ si,
                                          float* __restrict__ dr, float* __restrict__ di,
                                          const float* __restrict__ Ul) {
  const int t = threadIdx.x;
  const int lane = t & 63;
  const int wv = t >> 6;                       // m{11,10}
  const int b = blockIdx.x >> 4;
  const int tile = blockIdx.x & 15;            // m{15..12}
  const size_t bb = (size_t)b << 16;
  const int hi = (tile << 12) | (wv << 10) | (lane << 2);   // m bits 15..10, 7..2
  float xr[16], xi[16];                        // a = k*4 + e

  if (GATHER) {
    const bool sw = lane & 1;                  // j bit 2
    #pragma unroll
    for (int k = 0; k < 4; ++k) {
      const int j = hi | (k << 8);
      const int a4 = (j ^ (j >> 1)) & ~3;
      const float4 vr = *(const float4*)(sr + bb + a4);
      const float4 vi = *(const float4*)(si + bb + a4);
      // src component = gray2(e) ^ (sw?2:0), gray2 = {0,1,3,2}
      xr[k*4+0] = sw ? vr.z : vr.x;  xi[k*4+0] = sw ? vi.z : vi.x;
      xr[k*4+1] = sw ? vr.w : vr.y;  xi[k*4+1] = sw ? vi.w : vi.y;
      xr[k*4+2] = sw ? vr.y : vr.w;  xi[k*4+2] = sw ? vi.y : vi.w;
      xr[k*4+3] = sw ? vr.x : vr.z;  xi[k*4+3] = sw ? vi.x : vi.z;
    }
  } else {
    #pragma unroll
    for (int k = 0; k < 4; ++k) {
      const float4 vr = *(const float4*)(sr + bb + (hi | (k << 8)));
      const float4 vi = *(const float4*)(si + bb + (hi | (k << 8)));
      xr[k*4+0]=vr.x; xr[k*4+1]=vr.y; xr[k*4+2]=vr.z; xr[k*4+3]=vr.w;
      xi[k*4+0]=vi.x; xi[k*4+1]=vi.y; xi[k*4+2]=vi.z; xi[k*4+3]=vi.w;
    }
  }

  { // w6 on m9 (k bit 1): pairs (k, k|2)
    const G8 U = loadG(Ul + 6*8);
    #pragma unroll
    for (int e = 0; e < 4; ++e) {
      cmul2(U, xr[0+e], xi[0+e], xr[8+e],  xi[8+e]);
      cmul2(U, xr[4+e], xi[4+e], xr[12+e], xi[12+e]);
    }
  }
  { // w7 on m8 (k bit 0): pairs (k, k|1)
    const G8 U = loadG(Ul + 7*8);
    #pragma unroll
    for (int e = 0; e < 4; ++e) {
      cmul2(U, xr[0+e], xi[0+e], xr[4+e],  xi[4+e]);
      cmul2(U, xr[8+e], xi[8+e], xr[12+e], xi[12+e]);
    }
  }

  // w8..w13 on lane bits 5..0 (m bits 7..2): shuffle gates.
  #pragma unroll
  for (int g = 0; g < 6; ++g) {
    const int lb = 5 - g;
    const int mask = 1 << lb;
    const G8 U = loadG(Ul + (8 + g)*8);
    const bool hib = (lane >> lb) & 1;
    const float ar = hib ? U.r11 : U.r00, ai = hib ? U.i11 : U.i00;
    const float br = hib ? U.r10 : U.r01, bi = hib ? U.i10 : U.i01;
    #pragma unroll
    for (int a = 0; a < 16; ++a) {
      const float pr  = __shfl_xor(xr[a], mask);
      const float pim = __shfl_xor(xi[a], mask);
      const float nr = ar*xr[a] - ai*xi[a] + br*pr - bi*pim;
      const float ni = ar*xi[a] + ai*xr[a] + br*pim + bi*pr;
      xr[a] = nr; xi[a] = ni;
    }
  }

  { // w14 on m1 (e bit 1)
    const G8 U = loadG(Ul + 14*8);
    #pragma unroll
    for (int k = 0; k < 4; ++k) {
      cmul2(U, xr[k*4+0], xi[k*4+0], xr[k*4+2], xi[k*4+2]);
      cmul2(U, xr[k*4+1], xi[k*4+1], xr[k*4+3], xi[k*4+3]);
    }
  }
  { // w15 on m0 (e bit 0)
    const G8 U = loadG(Ul + 15*8);
    #pragma unroll
    for (int k = 0; k < 4; ++k) {
      cmul2(U, xr[k*4+0], xi[k*4+0], xr[k*4+1], xi[k*4+1]);
      cmul2(U, xr[k*4+2], xi[k*4+2], xr[k*4+3], xi[k*4+3]);
    }
  }

  #pragma unroll
  for (int k = 0; k < 4; ++k) {
    float4 vr, vi;
    vr.x=xr[k*4+0]; vr.y=xr[k*4+1]; vr.z=xr[k*4+2]; vr.w=xr[k*4+3];
    vi.x=xi[k*4+0]; vi.y=xi[k*4+1]; vi.z=xi[k*4+2]; vi.w=xi[k*4+3];
    *(float4*)(dr + bb + (hi | (k << 8))) = vr;
    *(float4*)(di + bb + (hi | (k << 8))) = vi;
  }
}

// Common index for kQ/kQF: local (non-batch) index with r=0.
__device__ __forceinline__ int kq_idx(int lane, int wv, int q) {
  return ((lane & 15) << 2) | ((lane & 48) << 6)   // m{5..2}, m{11,10}
       | (wv << 8)                                  // m{9,8}
       | ((q & 12) << 4) | (q & 3);                 // m{7,6}, m{1,0}
}

__device__ __forceinline__ void kq_gates(float* xr, float* xi, int lane,
                                         const float* __restrict__ Ul) {
  // w0..w3 on reg bits 3..0 (m15..m12)
  #pragma unroll
  for (int g = 0; g < 4; ++g) {
    const int kb = 3 - g;
    const G8 U = loadG(Ul + g*8);
    #pragma unroll
    for (int p = 0; p < 8; ++p) {
      const int i0 = ((p >> kb) << (kb + 1)) | (p & ((1 << kb) - 1));
      const int i1 = i0 | (1 << kb);
      cmul2(U, xr[i0], xi[i0], xr[i1], xi[i1]);
    }
  }
  // w4 on m11 (lane bit 5), w5 on m10 (lane bit 4): shuffle gates
  #pragma unroll
  for (int g = 0; g < 2; ++g) {
    const int lb = 5 - g;
    const int mask = 1 << lb;
    const G8 U = loadG(Ul + (4 + g)*8);
    const bool hib = (lane >> lb) & 1;
    const float ar = hib ? U.r11 : U.r00, ai = hib ? U.i11 : U.i00;
    const float br = hib ? U.r10 : U.r01, bi = hib ? U.i10 : U.i01;
    #pragma unroll
    for (int a = 0; a < 16; ++a) {
      const float pr  = __shfl_xor(xr[a], mask);
      const float pim = __shfl_xor(xi[a], mask);
      const float nr = ar*xr[a] - ai*xi[a] + br*pr - bi*pim;
      const float ni = ar*xi[a] + ai*xr[a] + br*pim + bi*pr;
      xr[a] = nr; xi[a] = ni;
    }
  }
}

// kQ: wires 0..5, 16 amps/thread, in-place.
__global__ void __launch_bounds__(256) kQ(float* __restrict__ r, float* __restrict__ im,
                                          const float* __restrict__ Ul) {
  const int t = threadIdx.x;
  const int lane = t & 63, wv = t >> 6;
  const int b = blockIdx.x >> 4, q = blockIdx.x & 15;
  const size_t base = ((size_t)b << 16) | kq_idx(lane, wv, q);
  float xr[16], xi[16];
  #pragma unroll
  for (int k = 0; k < 16; ++k) { xr[k] = r[base + (k << 12)]; xi[k] = im[base + (k << 12)]; }
  kq_gates(xr, xi, lane, Ul);
  #pragma unroll
  for (int k = 0; k < 16; ++k) { r[base + (k << 12)] = xr[k]; im[base + (k << 12)] = xi[k]; }
}

// kQF: final-layer kQ + fused PauliZ features (pending perm folded via gray-decode signs).
__global__ void __launch_bounds__(256) kQF(const float* __restrict__ r, const float* __restrict__ im,
                                           const float* __restrict__ Ul, float* __restrict__ feats) {
  const int t = threadIdx.x;
  const int lane = t & 63, wv = t >> 6;
  const int b = blockIdx.x >> 4, q = blockIdx.x & 15;
  const int idx = kq_idx(lane, wv, q);
  const size_t base = ((size_t)b << 16) | idx;
  float xr[16], xi[16];
  #pragma unroll
  for (int k = 0; k < 16; ++k) { xr[k] = r[base + (k << 12)]; xi[k] = im[base + (k << 12)]; }
  kq_gates(xr, xi, lane, Ul);
  // Reg-bit (m15..m12) suffix-parity classes: cut c=15,14,13, and c<=12.
  float T15=0.f, T14=0.f, T13=0.f, T12=0.f;
  #pragma unroll
  for (int k = 0; k < 16; ++k) {
    const float p = xr[k]*xr[k] + xi[k]*xi[k];
    const int b3=(k>>3)&1, b2=(k>>2)&1, b1=(k>>1)&1, b0=k&1;
    T15 += b3 ? -p : p;
    T14 += (b3^b2) ? -p : p;
    T13 += (b3^b2^b1) ? -p : p;
    T12 += (b3^b2^b1^b0) ? -p : p;
  }
  int w = idx;                                 // suffix parity of thread-const bits
  w ^= w >> 1; w ^= w >> 2; w ^= w >> 4; w ^= w >> 8;
  float f[16];
  #pragma unroll
  for (int qq = 0; qq < 16; ++qq) {
    const int c = 15 - qq;
    const float T = (qq == 0) ? T15 : (qq == 1) ? T14 : (qq == 2) ? T13 : T12;
    f[qq] = ((w >> c) & 1) ? -T : T;
  }
  #pragma unroll
  for (int qq = 0; qq < 16; ++qq) {
    float s = f[qq];
    s += __shfl_xor(s, 32); s += __shfl_xor(s, 16); s += __shfl_xor(s, 8);
    s += __shfl_xor(s, 4);  s += __shfl_xor(s, 2);  s += __shfl_xor(s, 1);
    f[qq] = s;
  }
  __shared__ float sf[64];
  if ((t & 63) == 0) {
    #pragma unroll
    for (int qq = 0; qq < 16; ++qq) sf[wv*16 + qq] = f[qq];
  }
  __syncthreads();
  if (t < 16) {
    const float s = sf[t] + sf[16 + t] + sf[32 + t] + sf[48 + t];
    atomicAdd(&feats[b*16 + t], s);
  }
}

__global__ void kHead(const float* __restrict__ feats, const float* __restrict__ w,
                      const float* __restrict__ bias, float* __restrict__ out) {
  const int b = threadIdx.x;
  if (b < 64) {
    float v = bias[0];
    #pragma unroll
    for (int q = 0; q < 16; ++q) v += feats[b*16 + q] * w[q];
    out[b] = v;
  }
}

extern "C" void kernel_launch(void* const* d_in, const int* in_sizes, int n_in,
                              void* d_out, int out_size, void* d_ws, size_t ws_size,
                              hipStream_t stream) {
  float* in_r = (float*)d_in[0];            // (64, 65536) fp32 — clobbered; harness restores
  float* in_i = (float*)d_in[1];
  const float* vp = (const float*)d_in[2];  // (3,16,6)
  const float* hw = (const float*)d_in[3];  // (1,16)
  const float* hb = (const float*)d_in[4];  // (1,)
  float* out = (float*)d_out;               // (64,) fp32

  float* ws_r  = (float*)d_ws;              // 4,194,304 floats
  float* ws_i  = ws_r + 4194304ull;
  float* Ubuf  = ws_i + 4194304ull;         // 48*8 floats
  float* feats = Ubuf + 384;                // 64*16 floats

  kPrep<<<1, 64, 0, stream>>>(vp, Ubuf, feats);
  // layer 0
  kP<0><<<1024, 256, 0, stream>>>(in_r, in_i, ws_r, ws_i, Ubuf + 0*128);
  kQ   <<<1024, 256, 0, stream>>>(ws_r, ws_i, Ubuf + 0*128);
  // layer 1 (perm of layer 0 folded into gather-load)
  kP<1><<<1024, 256, 0, stream>>>(ws_r, ws_i, in_r, in_i, Ubuf + 1*128);
  kQ   <<<1024, 256, 0, stream>>>(in_r, in_i, Ubuf + 1*128);
  // layer 2
  kP<1><<<1024, 256, 0, stream>>>(in_r, in_i, ws_r, ws_i, Ubuf + 2*128);
  kQF  <<<1024, 256, 0, stream>>>(ws_r, ws_i, Ubuf + 2*128, feats);
  kHead<<<1, 64, 0, stream>>>(feats, hw, hb, out);
}

// Round 4
// 222.588 us; speedup vs baseline: 1.1839x; 1.1839x over previous
//
#include <hip/hip_runtime.h>
#include <hip/hip_fp16.h>

// QuantumRegressionModel: 16-qubit statevector, 3 layers x (16 rotations + CNOT chain),
// PauliZ features + linear head. Batch 64, DIM 65536.
//
// Reductions (verified absmax=0 in rounds 2-3):
//  * Rotations in a layer commute -> split wires {6..15} (kP) and {0..5} (kQ).
//  * CNOT chain == Gray gather psi'[j] = psi[j ^ (j>>1)] -> folded into next kP's loads
//    (g maps aligned 4-amp windows to aligned 4-amp windows -> stays coalesced).
//  * Features on pre-perm state via suffix-parity signs -> fused into final kQ.
//  * Final state never materialized.
//
// Round-4 changes:
//  * Intermediate state fp16, interleaved (re,im) as __half2 per amp (compute fp32).
//    Unitary gates don't amplify rounding; feature error ~3e-6 << 3.9e-4 threshold.
//  * kQ layout fixed for coalescing: lanes[3:0]=m{3..0} (contiguous 64B segments),
//    lanes[5:4]=m{11,10} (wire-4/5 shuffles), waves=m{5,4}, block=m{9..6} x batch.
//    (Round-3 layout put m{1,0} in blockIdx -> stride-4 scatter, 4x WRITE_SIZE.)
//
// Wire q <-> amp-index bit (15-q).
// kP: block = m{15..12} x batch; waves = m{11,10}; lanes = m{7..2}; regs k=m{9,8},
//     e=m{1,0} (16B vector I/O). Gates: w6,w7 (k bits), w8..13 (shuffles), w14,w15 (e bits).
// kQ: regs = m{15..12} (w0..3), shuffles on lane bits 5,4 = m{11,10} (w4,w5).

struct G8 { float r00,i00,r01,i01,r10,i10,r11,i11; };

__device__ __forceinline__ G8 loadG(const float* __restrict__ p) {
  G8 g;
  g.r00=p[0]; g.i00=p[1]; g.r01=p[2]; g.i01=p[3];
  g.r10=p[4]; g.i10=p[5]; g.r11=p[6]; g.i11=p[7];
  return g;
}

__device__ __forceinline__ void cmul2(const G8& g, float& r0, float& i0, float& r1, float& i1) {
  const float nr0 = g.r00*r0 - g.i00*i0 + g.r01*r1 - g.i01*i1;
  const float ni0 = g.r00*i0 + g.i00*r0 + g.r01*i1 + g.i01*r1;
  const float nr1 = g.r10*r0 - g.i10*i0 + g.r11*r1 - g.i11*i1;
  const float ni1 = g.r10*i0 + g.i10*r0 + g.r11*i1 + g.i11*r1;
  r0=nr0; i0=ni0; r1=nr1; i1=ni1;
}

union HU { uint4 u; __half2 h[4]; };

// Build 48 fused unitaries U = Rz(tz)Ry(ty)Rx(tx); zero feats accumulator.
__global__ void kPrep(const float* __restrict__ vp, float* __restrict__ U,
                      float* __restrict__ feats) {
  const int i = threadIdx.x;
  if (i < 48) {
    const float tx = vp[i*6+0], ty = vp[i*6+1], tz = vp[i*6+2];
    float sx, cx, sy, cy, sz, cz;
    sincosf(0.5f*tx, &sx, &cx);
    sincosf(0.5f*ty, &sy, &cy);
    sincosf(0.5f*tz, &sz, &cz);
    const float m00r = cy*cx,  m00i = sy*sx;
    const float m01r = -sy*cx, m01i = -cy*sx;
    const float m10r = sy*cx,  m10i = -cy*sx;
    const float m11r = cy*cx,  m11i = -sy*sx;
    float* o = U + i*8;
    o[0] = cz*m00r + sz*m00i;  o[1] = cz*m00i - sz*m00r;
    o[2] = cz*m01r + sz*m01i;  o[3] = cz*m01i - sz*m01r;
    o[4] = cz*m10r - sz*m10i;  o[5] = cz*m10i + sz*m10r;
    o[6] = cz*m11r - sz*m11i;  o[7] = cz*m11i + sz*m11r;
  }
  for (int j = i; j < 1024; j += 64) feats[j] = 0.f;
}

// kP: wires 6..15 (bits 9..0), 16 amps/thread, no LDS/barriers.
// IN32: read fp32 planes (layer 0). GATHER: fold prev layer's CNOT perm into loads.
template<int GATHER, int IN32>
__global__ void __launch_bounds__(256) kP(const float* __restrict__ sr, const float* __restrict__ si,
                                          const __half2* __restrict__ s16,
                                          __half2* __restrict__ d16,
                                          const float* __restrict__ Ul) {
  const int t = threadIdx.x;
  const int lane = t & 63;
  const int wv = t >> 6;                         // m{11,10}
  const int b = blockIdx.x >> 4;
  const int tile = blockIdx.x & 15;              // m{15..12}
  const size_t bb = (size_t)b << 16;
  const int hi = (tile << 12) | (wv << 10) | (lane << 2);
  float xr[16], xi[16];                          // a = k*4 + e

  if constexpr (IN32) {
    #pragma unroll
    for (int k = 0; k < 4; ++k) {
      const int j = hi | (k << 8);
      const float4 vr = *(const float4*)(sr + bb + j);
      const float4 vi = *(const float4*)(si + bb + j);
      xr[k*4+0]=vr.x; xr[k*4+1]=vr.y; xr[k*4+2]=vr.z; xr[k*4+3]=vr.w;
      xi[k*4+0]=vi.x; xi[k*4+1]=vi.y; xi[k*4+2]=vi.z; xi[k*4+3]=vi.w;
    }
  } else if constexpr (GATHER) {
    const bool sw = lane & 1;                    // j bit 2
    #pragma unroll
    for (int k = 0; k < 4; ++k) {
      const int j = hi | (k << 8);
      const int a4 = (j ^ (j >> 1)) & ~3;        // source 4-amp window
      HU u; u.u = *(const uint4*)(s16 + bb + a4);
      // src component = gray2(e) ^ (sw?2:0), gray2 = {0,1,3,2}
      const float2 f0 = __half22float2(u.h[sw ? 2 : 0]);
      const float2 f1 = __half22float2(u.h[sw ? 3 : 1]);
      const float2 f2 = __half22float2(u.h[sw ? 1 : 3]);
      const float2 f3 = __half22float2(u.h[sw ? 0 : 2]);
      xr[k*4+0]=f0.x; xi[k*4+0]=f0.y;
      xr[k*4+1]=f1.x; xi[k*4+1]=f1.y;
      xr[k*4+2]=f2.x; xi[k*4+2]=f2.y;
      xr[k*4+3]=f3.x; xi[k*4+3]=f3.y;
    }
  } else {
    #pragma unroll
    for (int k = 0; k < 4; ++k) {
      HU u; u.u = *(const uint4*)(s16 + bb + (hi | (k << 8)));
      #pragma unroll
      for (int e = 0; e < 4; ++e) {
        const float2 f = __half22float2(u.h[e]);
        xr[k*4+e]=f.x; xi[k*4+e]=f.y;
      }
    }
  }

  { // w6 on m9 (k bit 1)
    const G8 U = loadG(Ul + 6*8);
    #pragma unroll
    for (int e = 0; e < 4; ++e) {
      cmul2(U, xr[0+e], xi[0+e], xr[8+e],  xi[8+e]);
      cmul2(U, xr[4+e], xi[4+e], xr[12+e], xi[12+e]);
    }
  }
  { // w7 on m8 (k bit 0)
    const G8 U = loadG(Ul + 7*8);
    #pragma unroll
    for (int e = 0; e < 4; ++e) {
      cmul2(U, xr[0+e], xi[0+e], xr[4+e],  xi[4+e]);
      cmul2(U, xr[8+e], xi[8+e], xr[12+e], xi[12+e]);
    }
  }

  // w8..w13 on lane bits 5..0 (m bits 7..2): shuffle gates.
  #pragma unroll
  for (int g = 0; g < 6; ++g) {
    const int lb = 5 - g;
    const int mask = 1 << lb;
    const G8 U = loadG(Ul + (8 + g)*8);
    const bool hib = (lane >> lb) & 1;
    const float ar = hib ? U.r11 : U.r00, ai = hib ? U.i11 : U.i00;
    const float br = hib ? U.r10 : U.r01, bi = hib ? U.i10 : U.i01;
    #pragma unroll
    for (int a = 0; a < 16; ++a) {
      const float pr  = __shfl_xor(xr[a], mask);
      const float pim = __shfl_xor(xi[a], mask);
      const float nr = ar*xr[a] - ai*xi[a] + br*pr - bi*pim;
      const float ni = ar*xi[a] + ai*xr[a] + br*pim + bi*pr;
      xr[a] = nr; xi[a] = ni;
    }
  }

  { // w14 on m1 (e bit 1)
    const G8 U = loadG(Ul + 14*8);
    #pragma unroll
    for (int k = 0; k < 4; ++k) {
      cmul2(U, xr[k*4+0], xi[k*4+0], xr[k*4+2], xi[k*4+2]);
      cmul2(U, xr[k*4+1], xi[k*4+1], xr[k*4+3], xi[k*4+3]);
    }
  }
  { // w15 on m0 (e bit 0)
    const G8 U = loadG(Ul + 15*8);
    #pragma unroll
    for (int k = 0; k < 4; ++k) {
      cmul2(U, xr[k*4+0], xi[k*4+0], xr[k*4+1], xi[k*4+1]);
      cmul2(U, xr[k*4+2], xi[k*4+2], xr[k*4+3], xi[k*4+3]);
    }
  }

  #pragma unroll
  for (int k = 0; k < 4; ++k) {
    HU u;
    u.h[0] = __floats2half2_rn(xr[k*4+0], xi[k*4+0]);
    u.h[1] = __floats2half2_rn(xr[k*4+1], xi[k*4+1]);
    u.h[2] = __floats2half2_rn(xr[k*4+2], xi[k*4+2]);
    u.h[3] = __floats2half2_rn(xr[k*4+3], xi[k*4+3]);
    *(uint4*)(d16 + bb + (hi | (k << 8))) = u.u;
  }
}

// kQ layout: lanes[3:0]=m{3..0}, lanes[5:4]=m{11,10}, wave=m{5,4}, block=m{9..6} x batch.
__device__ __forceinline__ int kq_idx(int lane, int wv, int q) {
  return (lane & 15) | ((lane & 48) << 6) | (wv << 4) | (q << 6);
}

__device__ __forceinline__ void kq_gates(float* xr, float* xi, int lane,
                                         const float* __restrict__ Ul) {
  // w0..w3 on reg bits 3..0 (m15..m12)
  #pragma unroll
  for (int g = 0; g < 4; ++g) {
    const int kb = 3 - g;
    const G8 U = loadG(Ul + g*8);
    #pragma unroll
    for (int p = 0; p < 8; ++p) {
      const int i0 = ((p >> kb) << (kb + 1)) | (p & ((1 << kb) - 1));
      const int i1 = i0 | (1 << kb);
      cmul2(U, xr[i0], xi[i0], xr[i1], xi[i1]);
    }
  }
  // w4 on m11 (lane bit 5), w5 on m10 (lane bit 4): shuffle gates
  #pragma unroll
  for (int g = 0; g < 2; ++g) {
    const int lb = 5 - g;
    const int mask = 1 << lb;
    const G8 U = loadG(Ul + (4 + g)*8);
    const bool hib = (lane >> lb) & 1;
    const float ar = hib ? U.r11 : U.r00, ai = hib ? U.i11 : U.i00;
    const float br = hib ? U.r10 : U.r01, bi = hib ? U.i10 : U.i01;
    #pragma unroll
    for (int a = 0; a < 16; ++a) {
      const float pr  = __shfl_xor(xr[a], mask);
      const float pim = __shfl_xor(xi[a], mask);
      const float nr = ar*xr[a] - ai*xi[a] + br*pr - bi*pim;
      const float ni = ar*xi[a] + ai*xr[a] + br*pim + bi*pr;
      xr[a] = nr; xi[a] = ni;
    }
  }
}

// kQ: wires 0..5, 16 amps/thread, in-place on fp16 state.
__global__ void __launch_bounds__(256) kQ(__half2* __restrict__ st,
                                          const float* __restrict__ Ul) {
  const int t = threadIdx.x;
  const int lane = t & 63, wv = t >> 6;
  const int b = blockIdx.x >> 4, q = blockIdx.x & 15;
  const size_t base = ((size_t)b << 16) | kq_idx(lane, wv, q);
  float xr[16], xi[16];
  #pragma unroll
  for (int k = 0; k < 16; ++k) {
    const float2 f = __half22float2(st[base + (k << 12)]);
    xr[k] = f.x; xi[k] = f.y;
  }
  kq_gates(xr, xi, lane, Ul);
  #pragma unroll
  for (int k = 0; k < 16; ++k)
    st[base + (k << 12)] = __floats2half2_rn(xr[k], xi[k]);
}

// kQF: final-layer kQ + fused PauliZ features (pending perm folded via suffix-parity signs).
__global__ void __launch_bounds__(256) kQF(const __half2* __restrict__ st,
                                           const float* __restrict__ Ul,
                                           float* __restrict__ feats) {
  const int t = threadIdx.x;
  const int lane = t & 63, wv = t >> 6;
  const int b = blockIdx.x >> 4, q = blockIdx.x & 15;
  const int idx = kq_idx(lane, wv, q);
  const size_t base = ((size_t)b << 16) | idx;
  float xr[16], xi[16];
  #pragma unroll
  for (int k = 0; k < 16; ++k) {
    const float2 f = __half22float2(st[base + (k << 12)]);
    xr[k] = f.x; xi[k] = f.y;
  }
  kq_gates(xr, xi, lane, Ul);
  // Reg-bit (m15..m12) suffix-parity classes.
  float T15=0.f, T14=0.f, T13=0.f, T12=0.f;
  #pragma unroll
  for (int k = 0; k < 16; ++k) {
    const float p = xr[k]*xr[k] + xi[k]*xi[k];
    const int b3=(k>>3)&1, b2=(k>>2)&1, b1=(k>>1)&1, b0=k&1;
    T15 += b3 ? -p : p;
    T14 += (b3^b2) ? -p : p;
    T13 += (b3^b2^b1) ? -p : p;
    T12 += (b3^b2^b1^b0) ? -p : p;
  }
  int w = idx;                                 // suffix parity of thread-constant bits
  w ^= w >> 1; w ^= w >> 2; w ^= w >> 4; w ^= w >> 8;
  float f[16];
  #pragma unroll
  for (int qq = 0; qq < 16; ++qq) {
    const int c = 15 - qq;
    const float T = (qq == 0) ? T15 : (qq == 1) ? T14 : (qq == 2) ? T13 : T12;
    f[qq] = ((w >> c) & 1) ? -T : T;
  }
  #pragma unroll
  for (int qq = 0; qq < 16; ++qq) {
    float s = f[qq];
    s += __shfl_xor(s, 32); s += __shfl_xor(s, 16); s += __shfl_xor(s, 8);
    s += __shfl_xor(s, 4);  s += __shfl_xor(s, 2);  s += __shfl_xor(s, 1);
    f[qq] = s;
  }
  __shared__ float sf[64];
  if ((t & 63) == 0) {
    #pragma unroll
    for (int qq = 0; qq < 16; ++qq) sf[wv*16 + qq] = f[qq];
  }
  __syncthreads();
  if (t < 16) {
    const float s = sf[t] + sf[16 + t] + sf[32 + t] + sf[48 + t];
    atomicAdd(&feats[b*16 + t], s);
  }
}

__global__ void kHead(const float* __restrict__ feats, const float* __restrict__ w,
                      const float* __restrict__ bias, float* __restrict__ out) {
  const int b = threadIdx.x;
  if (b < 64) {
    float v = bias[0];
    #pragma unroll
    for (int q = 0; q < 16; ++q) v += feats[b*16 + q] * w[q];
    out[b] = v;
  }
}

extern "C" void kernel_launch(void* const* d_in, const int* in_sizes, int n_in,
                              void* d_out, int out_size, void* d_ws, size_t ws_size,
                              hipStream_t stream) {
  const float* in_r = (const float*)d_in[0];  // (64, 65536) fp32
  const float* in_i = (const float*)d_in[1];
  const float* vp = (const float*)d_in[2];    // (3,16,6)
  const float* hw = (const float*)d_in[3];    // (1,16)
  const float* hb = (const float*)d_in[4];    // (1,)
  float* out = (float*)d_out;                 // (64,) fp32

  __half2* st0 = (__half2*)d_ws;              // 4,194,304 amps, 16 MB
  __half2* st1 = st0 + 4194304ull;            // 16 MB
  float* Ubuf  = (float*)(st1 + 4194304ull);  // 48*8 floats
  float* feats = Ubuf + 384;                  // 64*16 floats

  kPrep<<<1, 64, 0, stream>>>(vp, Ubuf, feats);
  // layer 0
  kP<0,1><<<1024, 256, 0, stream>>>(in_r, in_i, nullptr, st0, Ubuf + 0*128);
  kQ     <<<1024, 256, 0, stream>>>(st0, Ubuf + 0*128);
  // layer 1 (perm of layer 0 folded into gather-load)
  kP<1,0><<<1024, 256, 0, stream>>>(nullptr, nullptr, st0, st1, Ubuf + 1*128);
  kQ     <<<1024, 256, 0, stream>>>(st1, Ubuf + 1*128);
  // layer 2
  kP<1,0><<<1024, 256, 0, stream>>>(nullptr, nullptr, st1, st0, Ubuf + 2*128);
  kQF    <<<1024, 256, 0, stream>>>(st0, Ubuf + 2*128, feats);
  kHead<<<1, 64, 0, stream>>>(feats, hw, hb, out);
}